// Round 4
// baseline (506.144 us; speedup 1.0000x reference)
//
#include <hip/hip_runtime.h>
#include <stdint.h>

// Problem constants
#define B 2048
#define S 201
#define HALF 100                 // S/2
#define D 128
#define BS (B * S)               // 411648
#define OFF_POS (BS * D)         // 52690944  : pos_enc starts here (floats)
#define OFF_VT  (2 * OFF_POS)    // 105381888 : visited_time (floats)
#define OFF_T2  (OFF_VT + BS)    // 105793536 : top2 (floats, 2 per bs)
#define EMB_F4  (BS * (D / 4))   // 13172736  : float4 elements per [B,S,D] tensor

#define TPB 256
#define NB_B 4096                // kB grid

typedef float vf4 __attribute__((ext_vector_type(4)));

// ---------------- Kernel A: pointer chase only (32 blocks, 64 batches each) --------
// Writes compact staging to ws: vt u8 at [0,BS), t2 u16 at [BS, BS+2*BS).
__global__ __launch_bounds__(TPB) void kA(const int* __restrict__ sol,
                                          uint8_t* __restrict__ ws) {
    __shared__ uint8_t  s_sol[64 * S];
    __shared__ uint8_t  s_nx [64 * (HALF + 1)];
    __shared__ uint8_t  s_pv [64 * (HALF + 1)];
    __shared__ uint8_t  s_vis[64 * S];
    __shared__ uint16_t s_t2 [64 * S];
    const int tid = threadIdx.x;
    const int b0  = blockIdx.x * 64;

    for (int idx = tid; idx < 64 * S; idx += TPB) {
        s_sol[idx] = (uint8_t)sol[b0 * S + idx];
        s_vis[idx] = 0;
        s_t2[idx]  = 0;
    }
    __syncthreads();

    if (tid < 64) {
        uint8_t*  sl  = s_sol + tid * S;
        uint8_t*  nx  = s_nx  + tid * (HALF + 1);
        uint8_t*  pv  = s_pv  + tid * (HALF + 1);
        uint8_t*  vis = s_vis + tid * S;
        uint16_t* t2  = s_t2  + tid * S;

        int pre = 0;
        int head = 0, second = 1;   // invariant: head==0 -> second==1; 1 open -> second==0
        unsigned long long m0 = 0, m1 = 0;  // open-pickup bitmask (1..100)

        for (int i = 0; i < S; ++i) {
            int cur = sl[pre];
            vis[cur] = (uint8_t)(i + 1);
            if (cur != 0) {
                if (cur <= HALF) {
                    nx[cur]  = (uint8_t)head;
                    pv[head] = (uint8_t)cur;
                    second = head;
                    head   = cur;
                    if (cur < 64) m0 |= 1ull << cur; else m1 |= 1ull << (cur - 64);
                } else {
                    int q = cur - HALF;
                    bool in = (q < 64) ? ((m0 >> q) & 1ull) : ((m1 >> (q - 64)) & 1ull);
                    if (in) {
                        if (q < 64) m0 &= ~(1ull << q); else m1 &= ~(1ull << (q - 64));
                        if (q == head) {
                            head = second;
                            second = (head == 0) ? 1 : (int)nx[head];
                        } else if (q == second) {
                            int n2 = nx[q];
                            nx[head] = (uint8_t)n2;
                            pv[n2]   = (uint8_t)head;
                            second = n2;
                        } else {
                            int p = pv[q], n2 = nx[q];
                            nx[p]  = (uint8_t)n2;
                            pv[n2] = (uint8_t)p;
                        }
                    }
                }
            }
            t2[cur] = (uint16_t)(head | (second << 8));
            pre = cur;
        }
    }
    __syncthreads();

    uint16_t* t2_ws = (uint16_t*)(ws + BS);
    for (int idx = tid; idx < 64 * S; idx += TPB) {
        ws[b0 * S + idx]    = s_vis[idx];
        t2_ws[b0 * S + idx] = s_t2[idx];
    }
}

// ---------------- Kernel B: fused streaming (no LDS, plain stores) -----------------
// x_emb [B,S,D], pos_enc [B,S,D], vt float [B,S], top2 float2 [B,S]
__global__ __launch_bounds__(TPB) void kB(const float* __restrict__ x,
                                          const float* __restrict__ W,
                                          const float* __restrict__ pattern,
                                          const uint8_t* __restrict__ ws,
                                          float* __restrict__ out) {
    const int tid   = (int)(blockIdx.x * TPB + threadIdx.x);
    const int nthr  = NB_B * TPB;

    // W fragment for this thread's 4 output dims (d4 constant across grid-stride)
    const int d4 = tid & 31;
    const float4* W4 = (const float4*)W;
    float4 w0 = W4[d4 * 2];
    float4 w1 = W4[d4 * 2 + 1];

    const float2* x2 = (const float2*)x;
    const vf4* p4 = (const vf4*)pattern;
    vf4* oe = (vf4*)out;
    vf4* op = (vf4*)(out + OFF_POS);

    for (int idx4 = tid; idx4 < EMB_F4; idx4 += nthr) {
        int bs = idx4 >> 5;
        // x embedding
        float2 xv = x2[bs];
        vf4 o;
        o.x = xv.x * w0.x + xv.y * w0.y;
        o.y = xv.x * w0.z + xv.y * w0.w;
        o.z = xv.x * w1.x + xv.y * w1.y;
        o.w = xv.x * w1.z + xv.y * w1.w;
        oe[idx4] = o;
        // pos_enc gather
        int vt = ws[bs];                      // 1..201
        int row = (vt >= S) ? (vt - S) : vt;  // vt % S
        op[idx4] = p4[row * 32 + d4];
    }

    // vt float + top2 float2 expansion
    const uint16_t* t2_ws = (const uint16_t*)(ws + BS);
    float*  ovt = out + OFF_VT;
    float2* ot2 = (float2*)(out + OFF_T2);
    for (int idx = tid; idx < BS; idx += nthr) {
        ovt[idx] = (float)ws[idx];
        int t = t2_ws[idx];
        ot2[idx] = make_float2((float)(t & 255), (float)(t >> 8));
    }
}

extern "C" void kernel_launch(void* const* d_in, const int* in_sizes, int n_in,
                              void* d_out, int out_size, void* d_ws, size_t ws_size,
                              hipStream_t stream) {
    const float* x       = (const float*)d_in[0];   // [2048,201,2] f32
    const int*   sol     = (const int*)d_in[1];     // [2048,201] int
    const float* W       = (const float*)d_in[2];   // [128,2] f32
    const float* pattern = (const float*)d_in[3];   // [201,128] f32
    float* out = (float*)d_out;
    uint8_t* ws = (uint8_t*)d_ws;                   // 3*BS bytes staging

    hipLaunchKernelGGL(kA, dim3(32), dim3(TPB), 0, stream, sol, ws);
    hipLaunchKernelGGL(kB, dim3(NB_B), dim3(TPB), 0, stream, x, W, pattern, ws, out);
}